// Round 1
// baseline (612.902 us; speedup 1.0000x reference)
//
#include <hip/hip_runtime.h>
#include <hip/hip_bf16.h>
#include <hip/hip_cooperative_groups.h>

// MDTA: LN -> 1x1 conv (QKV) -> dw3x3 -> spatial attention (N=4096, d=24, 8 heads) -> proj + residual
// Round 12: single cooperative mega-kernel. All 5 phases (bodies verbatim from the verified
// 5-kernel pipeline) run in ONE launch with 4 grid.sync()s, eliminating 4 kernel boundaries
// (drain + ramp + graph node latency) which the floor-vs-measured gap (~100us over ~30us of
// real work, with every kernel <41us) attributes the time to. 1024 blocks x 256 thr = 4
// blocks/CU co-resident (<=128 VGPR via launch_bounds(256,4), 12.8KB LDS union). Host-side
// fallback to the original 5-kernel pipeline if the cooperative launch is rejected.

typedef __bf16 bf16;
typedef __bf16 bf16x2 __attribute__((ext_vector_type(2)));
typedef __bf16 bf16x4 __attribute__((ext_vector_type(4)));
typedef __bf16 bf16x8 __attribute__((ext_vector_type(8)));
typedef float f32x4 __attribute__((ext_vector_type(4)));

#define C_DIM 192
#define N_PIX 4096
#define HEADS 8
#define DHEAD 24
#define DPAD 32
#define C3 576
#define NSPLIT 8
#define SMEM_BYTES 12800   // max over phases: prep 2048, dwconv 10240, flash 8192, proj 12800

__device__ inline float fast_exp2(float x) {
#if __has_builtin(__builtin_amdgcn_exp2f)
    return __builtin_amdgcn_exp2f(x);
#else
    return exp2f(x);
#endif
}

__device__ inline f32x4 mfma16(bf16x8 a, bf16x8 b, f32x4 c) {
    return __builtin_amdgcn_mfma_f32_16x16x32_bf16(a, b, c, 0, 0, 0);
}

// ---------------- phase 0: LayerNorm (vb 0..255) + weight prep (vb 256..687) ----------------
__device__ __forceinline__ void phase_prep(int b, int t, char* sm,
                                           const float* __restrict__ x,
                                           const float* __restrict__ gamma,
                                           const float* __restrict__ beta,
                                           bf16* __restrict__ xln_t,
                                           const float* __restrict__ wqkv,
                                           const float* __restrict__ wproj,
                                           bf16* __restrict__ wqkv_b,
                                           bf16* __restrict__ wproj_b,
                                           float* __restrict__ maxk2) {
    if (b >= 256) {
        if (b < 688) {
            int idx = (b - 256) * 256 + t;
            if (idx < C3 * C_DIM) wqkv_b[idx] = (bf16)wqkv[idx];
            if (idx < C_DIM * C_DIM) wproj_b[idx] = (bf16)wproj[idx];
            if (b == 256 && t < 8) maxk2[t] = 0.0f;
        }
        return;
    }
    float* sred = (float*)sm;          // 256 floats
    float* ssred = sred + 256;         // 256 floats (2KB total)
    int pixg = t & 15, cgi = t >> 4;   // 16 pixels x 16 channel-groups of 12
    int p = b * 16 + pixg;
    float v[12];
    float s = 0.f, ss = 0.f;
    for (int j = 0; j < 12; ++j) {
        float f = x[(cgi * 12 + j) * N_PIX + p];
        v[j] = f; s += f; ss += f * f;
    }
    sred[t] = s; ssred[t] = ss;
    __syncthreads();
    float S = 0.f, SS = 0.f;
    for (int k = 0; k < 16; ++k) { S += sred[k * 16 + pixg]; SS += ssred[k * 16 + pixg]; }
    float mean = S * (1.0f / C_DIM);
    float var = SS * (1.0f / C_DIM) - mean * mean;
    float rstd = rsqrtf(var + 1e-5f);
    for (int g = 0; g < 3; ++g) {
        bf16x4 w;
        for (int j = 0; j < 4; ++j) {
            int c = cgi * 12 + g * 4 + j;
            w[j] = (bf16)((v[g * 4 + j] - mean) * rstd * gamma[c] + beta[c]);
        }
        *(bf16x4*)(xln_t + p * C_DIM + cgi * 12 + g * 4) = w;
    }
}

// ---------------- phase 1: GEMM (64x64 tile): qkv[576,4096] = wqkv[576,192] * xln[4096,192]^T ----------------
__device__ __forceinline__ void phase_gemm192(int vb, int tid,
                                              const bf16* __restrict__ A,
                                              const bf16* __restrict__ BT,
                                              bf16* __restrict__ outb) {
    const int K = 192;
    int n0 = (vb & 63) * 64;
    int m0 = (vb >> 6) * 64;
    int wave = tid >> 6, lane = tid & 63;
    int l16 = lane & 15, quad = lane >> 4;
    int wm = (wave >> 1) * 32, wn = (wave & 1) * 32;
    f32x4 acc[2][2] = {};
    for (int kk = 0; kk < K; kk += 32) {
        bf16x8 a0 = *(const bf16x8*)(A + (m0 + wm + l16) * K + kk + quad * 8);
        bf16x8 a1 = *(const bf16x8*)(A + (m0 + wm + 16 + l16) * K + kk + quad * 8);
        bf16x8 b0 = *(const bf16x8*)(BT + (n0 + wn + l16) * K + kk + quad * 8);
        bf16x8 b1 = *(const bf16x8*)(BT + (n0 + wn + 16 + l16) * K + kk + quad * 8);
        acc[0][0] = mfma16(a0, b0, acc[0][0]);
        acc[0][1] = mfma16(a0, b1, acc[0][1]);
        acc[1][0] = mfma16(a1, b0, acc[1][0]);
        acc[1][1] = mfma16(a1, b1, acc[1][1]);
    }
    for (int i = 0; i < 2; ++i)
        for (int j = 0; j < 2; ++j)
            for (int r = 0; r < 4; ++r) {
                int row = m0 + wm + i * 16 + quad * 4 + r;
                int col = n0 + wn + j * 16 + l16;
                outb[(size_t)row * N_PIX + col] = (bf16)acc[i][j][r];
            }
}

// ---------------- phase 2: depthwise 3x3 + bias; q/k stores via LDS transpose ----------------
__device__ __forceinline__ void phase_dwconv(int bx, int t, char* sm,
                                             const bf16* __restrict__ qkv,
                                             const float* __restrict__ wdw,
                                             const float* __restrict__ bdw,
                                             bf16* __restrict__ qt,
                                             bf16* __restrict__ kt,
                                             bf16* __restrict__ vl,
                                             float* __restrict__ maxk2) {
    float (*k2s)[64] = (float (*)[64])sm;          // 24*64*4 = 6144 B
    bf16* stg = (bf16*)(sm + 6144);                // 64*DPAD*2 = 4096 B
    int part = bx >> 9;            // 512 blocks per part
    int h = (bx >> 6) & 7;
    int y = bx & 63;
    int ch_local = t >> 3;         // 0..31 (24 active)
    int seg = t & 7;
    int px0 = seg * 8;
    bool active = ch_local < 24;

    float acc[8];
    if (active) {
        int ch = part * C_DIM + h * DHEAD + ch_local;
        const bf16* in = qkv + (size_t)ch * N_PIX;
        float w[9];
        for (int i = 0; i < 9; ++i) w[i] = wdw[ch * 9 + i];
        float bias = bdw[ch];
        float rowv[3][10];
        for (int r = 0; r < 3; ++r) {
            int yy = y + r - 1;
            if (yy >= 0 && yy < 64) {
                bf16x8 v8 = *(const bf16x8*)(in + yy * 64 + px0);
                for (int j = 0; j < 8; ++j) rowv[r][j + 1] = (float)v8[j];
                rowv[r][0] = (seg > 0) ? (float)in[yy * 64 + px0 - 1] : 0.f;
                rowv[r][9] = (seg < 7) ? (float)in[yy * 64 + px0 + 8] : 0.f;
            } else {
                for (int j = 0; j < 10; ++j) rowv[r][j] = 0.f;
            }
        }
        for (int j = 0; j < 8; ++j) {
            float a = bias;
            for (int r = 0; r < 3; ++r)
                a += w[r * 3 + 0] * rowv[r][j] + w[r * 3 + 1] * rowv[r][j + 1]
                   + w[r * 3 + 2] * rowv[r][j + 2];
            acc[j] = a;
        }
    }

    if (part == 2) {
        if (active) {
            bf16x8 v8;
            for (int j = 0; j < 8; ++j) v8[j] = (bf16)acc[j];
            *(bf16x8*)(vl + ((size_t)(h * DPAD + ch_local)) * N_PIX + y * 64 + px0) = v8;
        } else {
            int i = t - 192;           // pad rows 24..31 x 8 segments
            int dd = 24 + (i >> 3);
            int s2 = i & 7;
            bf16 val = (bf16)((dd == 24) ? 1.0f : 0.0f);
            bf16x8 v8;
            for (int j = 0; j < 8; ++j) v8[j] = val;
            *(bf16x8*)(vl + ((size_t)(h * DPAD + dd)) * N_PIX + y * 64 + s2 * 8) = v8;
        }
    } else {
        if (active) {
            for (int j = 0; j < 8; ++j)
                stg[(px0 + j) * DPAD + ch_local] = (bf16)acc[j];
        } else {
            int i = t - 192;           // px = i: zero pad ch 24..31
            bf16x8 z;
            for (int j = 0; j < 8; ++j) z[j] = (bf16)0.0f;
            *(bf16x8*)(stg + i * DPAD + 24) = z;
        }
        if (part == 1 && active)
            for (int j = 0; j < 8; ++j) k2s[ch_local][px0 + j] = acc[j] * acc[j];
        __syncthreads();
        bf16* dst = (part == 0 ? qt : kt) + ((size_t)h * N_PIX + y * 64) * DPAD;
        *(bf16x8*)(dst + t * 8) = *(const bf16x8*)(stg + t * 8);
        if (part == 1 && t < 64) {
            float s = 0.f;
            for (int c = 0; c < 24; ++c) s += k2s[c][t];
            for (int off = 1; off < 64; off <<= 1)
                s = fmaxf(s, __shfl_xor(s, off, 64));
            if (t == 0) atomicMax((unsigned int*)(maxk2 + h), __float_as_uint(s));
        }
        __syncthreads();   // protect stg/k2s reuse before leaving the phase body
    }
}

// ---------------- phase 3: flash attention, K-prefetch pipeline, split-K=8 ----------------
__device__ __forceinline__ void phase_flash(int vb, int tid, char* sm,
                                            const bf16* __restrict__ qt,
                                            const bf16* __restrict__ kt,
                                            const bf16* __restrict__ vl,
                                            const float* __restrict__ temp,
                                            const float* __restrict__ maxk2,
                                            bf16* __restrict__ opart,
                                            bf16* __restrict__ lpart) {
    bf16* Plds = (bf16*)sm;                  // 4*1024 bf16 = 8192 B
    int wave = tid >> 6, lane = tid & 63;
    int l16 = lane & 15, quad = lane >> 4;
    int head = vb & 7;               // block -> XCD round-robin: head pinned per XCD
    int qb = (vb >> 3) & 15;
    int split = vb >> 7;             // 0..7
    int nbase = qb * 256 + wave * 64;
    float tl = temp[head] * 1.44269504f;

    const bf16* qrow = qt + ((size_t)head * N_PIX + nbase) * DPAD;
    bf16x8 aq[4];
    for (int f = 0; f < 4; ++f)
        aq[f] = *(const bf16x8*)(qrow + (size_t)(f * 16 + l16) * DPAD + quad * 8);

    float mk2 = maxk2[head];
    float Bb[4];
    for (int f = 0; f < 4; ++f) {
        float q2 = 0.f;
        for (int j = 0; j < 8; ++j) { float v = (float)aq[f][j]; q2 += v * v; }
        q2 += __shfl_xor(q2, 16, 64);
        q2 += __shfl_xor(q2, 32, 64);
        Bb[f] = fabsf(tl) * sqrtf(q2 * mk2) + 1.0f;
    }

    const bf16* kbase = kt + (size_t)head * N_PIX * DPAD;
    const bf16* vbase = vl + (size_t)head * DPAD * N_PIX;
    bf16* pw = Plds + wave * 1024;

    f32x4 o0[4] = {}, o1[4] = {};

    const int NITER = 64 / NSPLIT;           // 8
    int mbase = split * NITER * 64;

    // prologue: K fragments for iter 0
    bf16x8 ak[4];
    for (int mt = 0; mt < 4; ++mt)
        ak[mt] = *(const bf16x8*)(kbase + (size_t)(mbase + mt * 16 + l16) * DPAD + quad * 8);

    #pragma unroll 2
    for (int it = 0; it < NITER; ++it) {
        int m0 = mbase + it * 64;
        bf16x8 av0 = *(const bf16x8*)(vbase + (size_t)l16 * N_PIX + m0 + quad * 8);
        bf16x8 av1 = *(const bf16x8*)(vbase + (size_t)(16 + l16) * N_PIX + m0 + quad * 8);
        bf16x8 av2 = *(const bf16x8*)(vbase + (size_t)l16 * N_PIX + m0 + 32 + quad * 8);
        bf16x8 av3 = *(const bf16x8*)(vbase + (size_t)(16 + l16) * N_PIX + m0 + 32 + quad * 8);
        bf16x8 akn[4];
        if (it + 1 < NITER) {
            int m1 = m0 + 64;
            for (int mt = 0; mt < 4; ++mt)
                akn[mt] = *(const bf16x8*)(kbase + (size_t)(m1 + mt * 16 + l16) * DPAD + quad * 8);
        }

        for (int f = 0; f < 4; ++f) {
            f32x4 z = {0.f, 0.f, 0.f, 0.f};
            f32x4 st[4];
            for (int mt = 0; mt < 4; ++mt) st[mt] = mfma16(ak[mt], aq[f], z);
            for (int mt = 0; mt < 4; ++mt) {
                bf16x4 pk;
                for (int r = 0; r < 4; ++r)
                    pk[r] = (bf16)fast_exp2(__builtin_fmaf(st[mt][r], tl, -Bb[f]));
                int chunk = mt * 2 + (quad >> 1);
                *(bf16x4*)(pw + (chunk * 16 + l16) * 8 + (quad & 1) * 4) = pk;
            }
            bf16x8 ap0 = *(const bf16x8*)(pw + (quad * 16 + l16) * 8);
            bf16x8 ap1 = *(const bf16x8*)(pw + ((4 + quad) * 16 + l16) * 8);
            o0[f] = mfma16(av0, ap0, o0[f]);
            o1[f] = mfma16(av1, ap0, o1[f]);
            o0[f] = mfma16(av2, ap1, o0[f]);
            o1[f] = mfma16(av3, ap1, o1[f]);
        }
        if (it + 1 < NITER)
            for (int mt = 0; mt < 4; ++mt) ak[mt] = akn[mt];
    }

    for (int f = 0; f < 4; ++f) {
        int n = nbase + f * 16 + l16;
        size_t rowo = ((size_t)(split * 8 + head) * N_PIX + n) * 24;
        bf16x4 w0;
        for (int r = 0; r < 4; ++r) w0[r] = (bf16)o0[f][r];
        *(bf16x4*)(opart + rowo + quad * 4) = w0;
        if (quad < 2) {
            bf16x4 w1;
            for (int r = 0; r < 4; ++r) w1[r] = (bf16)o1[f][r];
            *(bf16x4*)(opart + rowo + 16 + quad * 4) = w1;
        }
        if (quad == 2)
            lpart[(size_t)(split * 8 + head) * N_PIX + n] = (bf16)o1[f][0];
    }
}

// ---------------- phase 4: proj GEMM with fused split-K combine ----------------
__device__ __forceinline__ void phase_proj(int vb, int t, char* sm,
                                           const bf16* __restrict__ A,
                                           const bf16* __restrict__ opart,
                                           const bf16* __restrict__ lpart,
                                           float* __restrict__ outf,
                                           const float* __restrict__ resid) {
    bf16* Bld = (bf16*)sm;                   // 32*200*2 = 12800 B
    const int K = 192;
    int n0 = (vb % 128) * 32;
    int m0 = (vb / 128) * 64;
    {
        int h = t >> 5, nl = t & 31;
        int n = n0 + nl;
        float acc[24];
        for (int j = 0; j < 24; ++j) acc[j] = 0.f;
        float l = 0.f;
        for (int s = 0; s < NSPLIT; ++s) {
            const bf16* row = opart + ((size_t)(s * 8 + h) * N_PIX + n) * 24;
            bf16x8 a = *(const bf16x8*)(row);
            bf16x8 b = *(const bf16x8*)(row + 8);
            bf16x8 c = *(const bf16x8*)(row + 16);
            for (int j = 0; j < 8; ++j) {
                acc[j] += (float)a[j];
                acc[8 + j] += (float)b[j];
                acc[16 + j] += (float)c[j];
            }
            l += (float)lpart[(size_t)(s * 8 + h) * N_PIX + n];
        }
        float inv = 1.0f / l;
        bf16* dst = Bld + nl * 200 + h * 24;
        for (int g = 0; g < 3; ++g) {
            bf16x8 w;
            for (int j = 0; j < 8; ++j) w[j] = (bf16)(acc[g * 8 + j] * inv);
            *(bf16x8*)(dst + g * 8) = w;
        }
    }
    __syncthreads();
    int wave = t >> 6, lane = t & 63;
    int l16 = lane & 15, quad = lane >> 4;
    int mrow = m0 + wave * 16;
    float rv[8];
    for (int j = 0; j < 2; ++j)
        for (int r = 0; r < 4; ++r)
            rv[j * 4 + r] = resid[(size_t)(mrow + quad * 4 + r) * N_PIX + n0 + j * 16 + l16];
    f32x4 acc2[2] = {};
    for (int kk = 0; kk < K; kk += 32) {
        bf16x8 a = *(const bf16x8*)(A + (mrow + l16) * K + kk + quad * 8);
        bf16x8 b0 = *(const bf16x8*)(Bld + l16 * 200 + kk + quad * 8);
        bf16x8 b1 = *(const bf16x8*)(Bld + (16 + l16) * 200 + kk + quad * 8);
        acc2[0] = mfma16(a, b0, acc2[0]);
        acc2[1] = mfma16(a, b1, acc2[1]);
    }
    for (int j = 0; j < 2; ++j)
        for (int r = 0; r < 4; ++r) {
            int row = mrow + quad * 4 + r;
            int col = n0 + j * 16 + l16;
            outf[(size_t)row * N_PIX + col] = acc2[j][r] + rv[j * 4 + r];
        }
}

// ---------------- mega-kernel: all phases, 4 grid syncs ----------------
__global__ __launch_bounds__(256, 4) void mdta_mega(const float* __restrict__ x,
                                                    const float* __restrict__ gamma,
                                                    const float* __restrict__ beta,
                                                    const float* __restrict__ wqkv,
                                                    const float* __restrict__ wdw,
                                                    const float* __restrict__ bdw,
                                                    const float* __restrict__ wproj,
                                                    const float* __restrict__ temp,
                                                    float* __restrict__ out,
                                                    bf16* __restrict__ wqkv_b,
                                                    bf16* __restrict__ wproj_b,
                                                    bf16* __restrict__ xln,
                                                    bf16* __restrict__ qkv,
                                                    bf16* __restrict__ qt,
                                                    bf16* __restrict__ kt,
                                                    bf16* __restrict__ vl,
                                                    bf16* __restrict__ opart,
                                                    bf16* __restrict__ lpart,
                                                    float* __restrict__ maxk2) {
    __shared__ __align__(16) char sm[SMEM_BYTES];
    cooperative_groups::grid_group grid = cooperative_groups::this_grid();
    int bid = blockIdx.x;
    int t = threadIdx.x;

    phase_prep(bid, t, sm, x, gamma, beta, xln, wqkv, wproj, wqkv_b, wproj_b, maxk2);
    grid.sync();
    if (bid < 576) phase_gemm192(bid, t, wqkv_b, xln, qkv);
    grid.sync();
    for (int vb = bid; vb < 1536; vb += 1024)
        phase_dwconv(vb, t, sm, qkv, wdw, bdw, qt, kt, vl, maxk2);
    grid.sync();
    phase_flash(bid, t, sm, qt, kt, vl, temp, maxk2, opart, lpart);
    grid.sync();
    if (bid < 384) phase_proj(bid, t, sm, wproj_b, opart, lpart, out, x);
}

// ---------------- fallback wrappers (original 5-kernel pipeline) ----------------
__global__ __launch_bounds__(256) void prep_ln_k(const float* x, const float* gamma, const float* beta,
                                                 bf16* xln, const float* wqkv, const float* wproj,
                                                 bf16* wqkv_b, bf16* wproj_b, float* maxk2) {
    __shared__ __align__(16) char sm[2048];
    phase_prep(blockIdx.x, threadIdx.x, sm, x, gamma, beta, xln, wqkv, wproj, wqkv_b, wproj_b, maxk2);
}

__global__ __launch_bounds__(256) void gemm192_k(const bf16* A, const bf16* BT, bf16* outb) {
    phase_gemm192(blockIdx.y * 64 + blockIdx.x, threadIdx.x, A, BT, outb);
}

__global__ __launch_bounds__(256) void dwconv_k(const bf16* qkv, const float* wdw, const float* bdw,
                                                bf16* qt, bf16* kt, bf16* vl, float* maxk2) {
    __shared__ __align__(16) char sm[10240];
    phase_dwconv(blockIdx.x, threadIdx.x, sm, qkv, wdw, bdw, qt, kt, vl, maxk2);
}

__global__ __launch_bounds__(256, 4) void flash_k(const bf16* qt, const bf16* kt, const bf16* vl,
                                                  const float* temp, const float* maxk2,
                                                  bf16* opart, bf16* lpart) {
    __shared__ __align__(16) char sm[8192];
    phase_flash(blockIdx.x, threadIdx.x, sm, qt, kt, vl, temp, maxk2, opart, lpart);
}

__global__ __launch_bounds__(256) void proj_k(const bf16* A, const bf16* opart, const bf16* lpart,
                                              float* outf, const float* resid) {
    __shared__ __align__(16) char sm[12800];
    phase_proj(blockIdx.y * 128 + blockIdx.x, threadIdx.x, sm, A, opart, lpart, outf, resid);
}

extern "C" void kernel_launch(void* const* d_in, const int* in_sizes, int n_in,
                              void* d_out, int out_size, void* d_ws, size_t ws_size,
                              hipStream_t stream) {
    const float* x     = (const float*)d_in[0];
    const float* gamma = (const float*)d_in[1];
    const float* beta  = (const float*)d_in[2];
    const float* wqkv  = (const float*)d_in[3];
    const float* wdw   = (const float*)d_in[4];
    const float* bdw   = (const float*)d_in[5];
    const float* wproj = (const float*)d_in[6];
    const float* temp  = (const float*)d_in[7];
    float* out = (float*)d_out;

    char* ws = (char*)d_ws;
    bf16* wqkv_b  = (bf16*)(ws + 0);          // 221184
    bf16* wproj_b = (bf16*)(ws + 221184);     // 73728
    bf16* xln     = (bf16*)(ws + 294912);     // 1572864
    bf16* qkv     = (bf16*)(ws + 1867776);    // 4718592
    bf16* qt      = (bf16*)(ws + 6586368);    // 2097152
    bf16* kt      = (bf16*)(ws + 8683520);    // 2097152
    bf16* vl      = (bf16*)(ws + 10780672);   // 2097152
    bf16* opart   = (bf16*)(ws + 12877824);   // 8*8*4096*24*2 = 12582912
    bf16* lpart   = (bf16*)(ws + 25460736);   // 8*8*4096*2 = 524288
    float* maxk2  = (float*)(ws + 25985024);  // 32

    void* args[] = {
        (void*)&x, (void*)&gamma, (void*)&beta, (void*)&wqkv, (void*)&wdw, (void*)&bdw,
        (void*)&wproj, (void*)&temp, (void*)&out, (void*)&wqkv_b, (void*)&wproj_b,
        (void*)&xln, (void*)&qkv, (void*)&qt, (void*)&kt, (void*)&vl,
        (void*)&opart, (void*)&lpart, (void*)&maxk2
    };
    hipError_t err = hipLaunchCooperativeKernel((void*)mdta_mega, dim3(1024), dim3(256),
                                                args, 0, stream);
    if (err != hipSuccess) {
        // fallback: original verified 5-kernel pipeline
        prep_ln_k<<<688, 256, 0, stream>>>(x, gamma, beta, xln, wqkv, wproj, wqkv_b, wproj_b, maxk2);
        gemm192_k<<<dim3(64, 9), 256, 0, stream>>>(wqkv_b, xln, qkv);
        dwconv_k<<<1536, 256, 0, stream>>>(qkv, wdw, bdw, qt, kt, vl, maxk2);
        flash_k<<<NSPLIT * 128, 256, 0, stream>>>(qt, kt, vl, temp, maxk2, opart, lpart);
        proj_k<<<dim3(128, 3), 256, 0, stream>>>(wproj_b, opart, lpart, out, x);
    }
}

// Round 2
// 132.725 us; speedup vs baseline: 4.6178x; 4.6178x over previous
//
#include <hip/hip_runtime.h>
#include <hip/hip_bf16.h>

// MDTA: LN -> 1x1 conv (QKV) -> dw3x3 -> spatial attention (N=4096, d=24, 8 heads) -> proj + residual
// Round 13: revert from cooperative mega-kernel (533us: grid.sync spin/fence + VGPR squeeze = 4x
// regression). Back to the verified multi-kernel pipeline, minus one kernel: LayerNorm is fused
// into the QKV GEMM (each block LN-normalizes its own 64 pixels into LDS; 9x redundant across
// m-tiles but x is L2-resident), and f32->bf16 weight conversion is done inline by the GEMM
// consumers (weights L2-hot, reused 64x). Removes prep_ln kernel + xln/wqkv_b/wproj_b roundtrips.
// dwconv / flash_attn / proj-GEMM-core are byte-identical to the verified 134.6us baseline.

typedef __bf16 bf16;
typedef __bf16 bf16x2 __attribute__((ext_vector_type(2)));
typedef __bf16 bf16x4 __attribute__((ext_vector_type(4)));
typedef __bf16 bf16x8 __attribute__((ext_vector_type(8)));
typedef float f32x4 __attribute__((ext_vector_type(4)));

#define C_DIM 192
#define N_PIX 4096
#define HEADS 8
#define DHEAD 24
#define DPAD 32
#define C3 576
#define NSPLIT 8

__device__ inline float fast_exp2(float x) {
#if __has_builtin(__builtin_amdgcn_exp2f)
    return __builtin_amdgcn_exp2f(x);
#else
    return exp2f(x);
#endif
}

__device__ inline f32x4 mfma16(bf16x8 a, bf16x8 b, f32x4 c) {
    return __builtin_amdgcn_mfma_f32_16x16x32_bf16(a, b, c, 0, 0, 0);
}

// ---------------- fused LN + QKV GEMM (64x64 tile): qkv[576,4096] = wqkv[576,192] * LN(x)[4096,192]^T ----------------
// Each block: LN its 64 pixels (all 192 ch) into LDS Bt[64][200] bf16, then MFMA against
// inline-converted wqkv rows. LN reduction via shfl_xor(16/32) — the 4 lanes sharing l16 hold
// the 4 channel-segments of one pixel.
__global__ __launch_bounds__(256) void ln_qkv(const float* __restrict__ x,
                                              const float* __restrict__ gamma,
                                              const float* __restrict__ beta,
                                              const float* __restrict__ wqkv,
                                              bf16* __restrict__ qkvb,
                                              float* __restrict__ maxk2) {
    __shared__ __align__(16) bf16 Bt[64 * 200];   // 25.6 KB, +8 pad breaks 32-bank stride
    __shared__ float gs[C_DIM], bs[C_DIM];
    const int K = C_DIM;
    int n0 = blockIdx.x * 64;
    int m0 = blockIdx.y * 64;
    int t = threadIdx.x;
    if (t < C_DIM) { gs[t] = gamma[t]; bs[t] = beta[t]; }
    if (blockIdx.x == 0 && blockIdx.y == 0 && t < 8) maxk2[t] = 0.0f;
    __syncthreads();

    int lane = t & 63, wave = t >> 6;
    {
        int pl = wave * 16 + (lane & 15);       // pixel within tile, 0..63
        int seg = lane >> 4;                    // 0..3 -> 48 channels each
        int p = n0 + pl;
        float v[48];
        float s = 0.f, ss = 0.f;
        for (int j = 0; j < 48; ++j) {
            float f = x[(seg * 48 + j) * N_PIX + p];
            v[j] = f; s += f; ss += f * f;
        }
        s += __shfl_xor(s, 16, 64); s += __shfl_xor(s, 32, 64);
        ss += __shfl_xor(ss, 16, 64); ss += __shfl_xor(ss, 32, 64);
        float mean = s * (1.0f / C_DIM);
        float var = ss * (1.0f / C_DIM) - mean * mean;
        float rstd = rsqrtf(var + 1e-5f);
        bf16* dst = Bt + pl * 200 + seg * 48;
        for (int g = 0; g < 6; ++g) {
            bf16x8 w;
            for (int j = 0; j < 8; ++j) {
                int c = seg * 48 + g * 8 + j;
                w[j] = (bf16)((v[g * 8 + j] - mean) * rstd * gs[c] + bs[c]);
            }
            *(bf16x8*)(dst + g * 8) = w;
        }
    }
    __syncthreads();

    int l16 = lane & 15, quad = lane >> 4;
    int wm = (wave >> 1) * 32, wn = (wave & 1) * 32;
    f32x4 acc[2][2] = {};
    for (int kk = 0; kk < K; kk += 32) {
        const float* ar0 = wqkv + (m0 + wm + l16) * K + kk + quad * 8;
        const float* ar1 = wqkv + (m0 + wm + 16 + l16) * K + kk + quad * 8;
        bf16x8 a0, a1;
        for (int j = 0; j < 8; ++j) { a0[j] = (bf16)ar0[j]; a1[j] = (bf16)ar1[j]; }
        bf16x8 b0 = *(const bf16x8*)(Bt + (wn + l16) * 200 + kk + quad * 8);
        bf16x8 b1 = *(const bf16x8*)(Bt + (wn + 16 + l16) * 200 + kk + quad * 8);
        acc[0][0] = mfma16(a0, b0, acc[0][0]);
        acc[0][1] = mfma16(a0, b1, acc[0][1]);
        acc[1][0] = mfma16(a1, b0, acc[1][0]);
        acc[1][1] = mfma16(a1, b1, acc[1][1]);
    }
    for (int i = 0; i < 2; ++i)
        for (int j = 0; j < 2; ++j)
            for (int r = 0; r < 4; ++r) {
                int row = m0 + wm + i * 16 + quad * 4 + r;
                int col = n0 + wn + j * 16 + l16;
                qkvb[(size_t)row * N_PIX + col] = (bf16)acc[i][j][r];
            }
}

// ---------------- depthwise 3x3 + bias, vectorized; q/k stores via LDS transpose ----------------
__global__ __launch_bounds__(256) void dwconv(const bf16* __restrict__ qkv,
                                              const float* __restrict__ wdw,
                                              const float* __restrict__ bdw,
                                              bf16* __restrict__ qt,
                                              bf16* __restrict__ kt,
                                              bf16* __restrict__ vl,
                                              float* __restrict__ maxk2) {
    __shared__ float k2s[24][64];
    __shared__ bf16 stg[64 * DPAD];   // [px][ch], 4 KB
    int bx = blockIdx.x;
    int part = bx >> 9;            // 512 blocks per part
    int h = (bx >> 6) & 7;
    int y = bx & 63;
    int t = threadIdx.x;
    int ch_local = t >> 3;         // 0..31 (24 active)
    int seg = t & 7;
    int px0 = seg * 8;
    bool active = ch_local < 24;

    float acc[8];
    if (active) {
        int ch = part * C_DIM + h * DHEAD + ch_local;
        const bf16* in = qkv + (size_t)ch * N_PIX;
        float w[9];
        for (int i = 0; i < 9; ++i) w[i] = wdw[ch * 9 + i];
        float bias = bdw[ch];
        float rowv[3][10];
        for (int r = 0; r < 3; ++r) {
            int yy = y + r - 1;
            if (yy >= 0 && yy < 64) {
                bf16x8 v8 = *(const bf16x8*)(in + yy * 64 + px0);
                for (int j = 0; j < 8; ++j) rowv[r][j + 1] = (float)v8[j];
                rowv[r][0] = (seg > 0) ? (float)in[yy * 64 + px0 - 1] : 0.f;
                rowv[r][9] = (seg < 7) ? (float)in[yy * 64 + px0 + 8] : 0.f;
            } else {
                for (int j = 0; j < 10; ++j) rowv[r][j] = 0.f;
            }
        }
        for (int j = 0; j < 8; ++j) {
            float a = bias;
            for (int r = 0; r < 3; ++r)
                a += w[r * 3 + 0] * rowv[r][j] + w[r * 3 + 1] * rowv[r][j + 1]
                   + w[r * 3 + 2] * rowv[r][j + 2];
            acc[j] = a;
        }
    }

    if (part == 2) {
        if (active) {
            bf16x8 v8;
            for (int j = 0; j < 8; ++j) v8[j] = (bf16)acc[j];
            *(bf16x8*)(vl + ((size_t)(h * DPAD + ch_local)) * N_PIX + y * 64 + px0) = v8;
        } else {
            int i = t - 192;           // pad rows 24..31 x 8 segments
            int dd = 24 + (i >> 3);
            int s2 = i & 7;
            bf16 val = (bf16)((dd == 24) ? 1.0f : 0.0f);
            bf16x8 v8;
            for (int j = 0; j < 8; ++j) v8[j] = val;
            *(bf16x8*)(vl + ((size_t)(h * DPAD + dd)) * N_PIX + y * 64 + s2 * 8) = v8;
        }
    } else {
        if (active) {
            for (int j = 0; j < 8; ++j)
                stg[(px0 + j) * DPAD + ch_local] = (bf16)acc[j];
        } else {
            int i = t - 192;           // px = i: zero pad ch 24..31
            bf16x8 z;
            for (int j = 0; j < 8; ++j) z[j] = (bf16)0.0f;
            *(bf16x8*)(stg + i * DPAD + 24) = z;
        }
        if (part == 1 && active)
            for (int j = 0; j < 8; ++j) k2s[ch_local][px0 + j] = acc[j] * acc[j];
        __syncthreads();
        bf16* dst = (part == 0 ? qt : kt) + ((size_t)h * N_PIX + y * 64) * DPAD;
        *(bf16x8*)(dst + t * 8) = *(const bf16x8*)(stg + t * 8);
        if (part == 1 && t < 64) {
            float s = 0.f;
            for (int c = 0; c < 24; ++c) s += k2s[c][t];
            for (int off = 1; off < 64; off <<= 1)
                s = fmaxf(s, __shfl_xor(s, off, 64));
            if (t == 0) atomicMax((unsigned int*)(maxk2 + h), __float_as_uint(s));
        }
    }
}

// ---------------- flash attention: fat waves, K-prefetch pipeline, split-K=8 ----------------
__global__ __launch_bounds__(256, 4) void flash_attn(const bf16* __restrict__ qt,
                                                     const bf16* __restrict__ kt,
                                                     const bf16* __restrict__ vl,
                                                     const float* __restrict__ temp,
                                                     const float* __restrict__ maxk2,
                                                     bf16* __restrict__ opart,
                                                     bf16* __restrict__ lpart) {
    __shared__ __align__(16) bf16 Plds[4 * 1024];   // 2KB per wave: [chunk(8)][l16(16)][8]

    int tid = threadIdx.x;
    int wave = tid >> 6, lane = tid & 63;
    int l16 = lane & 15, quad = lane >> 4;
    int head = blockIdx.x & 7;               // block -> XCD round-robin: head pinned per XCD
    int qb = (blockIdx.x >> 3) & 15;
    int split = blockIdx.x >> 7;             // 0..7
    int nbase = qb * 256 + wave * 64;
    float tl = temp[head] * 1.44269504f;

    const bf16* qrow = qt + ((size_t)head * N_PIX + nbase) * DPAD;
    bf16x8 aq[4];
    for (int f = 0; f < 4; ++f)
        aq[f] = *(const bf16x8*)(qrow + (size_t)(f * 16 + l16) * DPAD + quad * 8);

    float mk2 = maxk2[head];
    float Bb[4];
    for (int f = 0; f < 4; ++f) {
        float q2 = 0.f;
        for (int j = 0; j < 8; ++j) { float v = (float)aq[f][j]; q2 += v * v; }
        q2 += __shfl_xor(q2, 16, 64);
        q2 += __shfl_xor(q2, 32, 64);
        Bb[f] = fabsf(tl) * sqrtf(q2 * mk2) + 1.0f;
    }

    const bf16* kbase = kt + (size_t)head * N_PIX * DPAD;
    const bf16* vbase = vl + (size_t)head * DPAD * N_PIX;
    bf16* pw = Plds + wave * 1024;

    f32x4 o0[4] = {}, o1[4] = {};

    const int NITER = 64 / NSPLIT;           // 8
    int mbase = split * NITER * 64;

    // prologue: K fragments for iter 0
    bf16x8 ak[4];
    for (int mt = 0; mt < 4; ++mt)
        ak[mt] = *(const bf16x8*)(kbase + (size_t)(mbase + mt * 16 + l16) * DPAD + quad * 8);

    #pragma unroll 2
    for (int it = 0; it < NITER; ++it) {
        int m0 = mbase + it * 64;
        // V fragments for this iter (consumed late -> latency self-hiding)
        bf16x8 av0 = *(const bf16x8*)(vbase + (size_t)l16 * N_PIX + m0 + quad * 8);
        bf16x8 av1 = *(const bf16x8*)(vbase + (size_t)(16 + l16) * N_PIX + m0 + quad * 8);
        bf16x8 av2 = *(const bf16x8*)(vbase + (size_t)l16 * N_PIX + m0 + 32 + quad * 8);
        bf16x8 av3 = *(const bf16x8*)(vbase + (size_t)(16 + l16) * N_PIX + m0 + 32 + quad * 8);
        // prefetch next iter's K fragments (the latency-exposed loads)
        bf16x8 akn[4];
        if (it + 1 < NITER) {
            int m1 = m0 + 64;
            for (int mt = 0; mt < 4; ++mt)
                akn[mt] = *(const bf16x8*)(kbase + (size_t)(m1 + mt * 16 + l16) * DPAD + quad * 8);
        }

        for (int f = 0; f < 4; ++f) {
            f32x4 z = {0.f, 0.f, 0.f, 0.f};
            f32x4 st[4];
            for (int mt = 0; mt < 4; ++mt) st[mt] = mfma16(ak[mt], aq[f], z);
            for (int mt = 0; mt < 4; ++mt) {
                bf16x4 pk;
                for (int r = 0; r < 4; ++r)
                    pk[r] = (bf16)fast_exp2(__builtin_fmaf(st[mt][r], tl, -Bb[f]));
                int chunk = mt * 2 + (quad >> 1);
                *(bf16x4*)(pw + (chunk * 16 + l16) * 8 + (quad & 1) * 4) = pk;
            }
            bf16x8 ap0 = *(const bf16x8*)(pw + (quad * 16 + l16) * 8);
            bf16x8 ap1 = *(const bf16x8*)(pw + ((4 + quad) * 16 + l16) * 8);
            o0[f] = mfma16(av0, ap0, o0[f]);
            o1[f] = mfma16(av1, ap0, o1[f]);
            o0[f] = mfma16(av2, ap1, o0[f]);
            o1[f] = mfma16(av3, ap1, o1[f]);
        }
        if (it + 1 < NITER)
            for (int mt = 0; mt < 4; ++mt) ak[mt] = akn[mt];
    }

    for (int f = 0; f < 4; ++f) {
        int n = nbase + f * 16 + l16;
        size_t rowo = ((size_t)(split * 8 + head) * N_PIX + n) * 24;
        bf16x4 w0;
        for (int r = 0; r < 4; ++r) w0[r] = (bf16)o0[f][r];
        *(bf16x4*)(opart + rowo + quad * 4) = w0;
        if (quad < 2) {
            bf16x4 w1;
            for (int r = 0; r < 4; ++r) w1[r] = (bf16)o1[f][r];
            *(bf16x4*)(opart + rowo + 16 + quad * 4) = w1;
        }
        if (quad == 2)
            lpart[(size_t)(split * 8 + head) * N_PIX + n] = (bf16)o1[f][0];
    }
}

// ---------------- proj GEMM with fused split-K combine; wproj converted inline ----------------
__global__ __launch_bounds__(256) void gemm_proj(const float* __restrict__ wproj,
                                                 const bf16* __restrict__ opart,
                                                 const bf16* __restrict__ lpart,
                                                 float* __restrict__ outf,
                                                 const float* __restrict__ resid) {
    __shared__ __align__(16) bf16 Bld[32 * 200];
    const int K = C_DIM;
    int n0 = blockIdx.x * 32;
    int m0 = blockIdx.y * 64;
    int t = threadIdx.x;
    {
        int h = t >> 5, nl = t & 31;
        int n = n0 + nl;
        float acc[24];
        for (int j = 0; j < 24; ++j) acc[j] = 0.f;
        float l = 0.f;
        for (int s = 0; s < NSPLIT; ++s) {
            const bf16* row = opart + ((size_t)(s * 8 + h) * N_PIX + n) * 24;
            bf16x8 a = *(const bf16x8*)(row);
            bf16x8 b = *(const bf16x8*)(row + 8);
            bf16x8 c = *(const bf16x8*)(row + 16);
            for (int j = 0; j < 8; ++j) {
                acc[j] += (float)a[j];
                acc[8 + j] += (float)b[j];
                acc[16 + j] += (float)c[j];
            }
            l += (float)lpart[(size_t)(s * 8 + h) * N_PIX + n];
        }
        float inv = 1.0f / l;
        bf16* dst = Bld + nl * 200 + h * 24;
        for (int g = 0; g < 3; ++g) {
            bf16x8 w;
            for (int j = 0; j < 8; ++j) w[j] = (bf16)(acc[g * 8 + j] * inv);
            *(bf16x8*)(dst + g * 8) = w;
        }
    }
    __syncthreads();
    int wave = t >> 6, lane = t & 63;
    int l16 = lane & 15, quad = lane >> 4;
    int mrow = m0 + wave * 16;
    float rv[8];
    for (int j = 0; j < 2; ++j)
        for (int r = 0; r < 4; ++r)
            rv[j * 4 + r] = resid[(size_t)(mrow + quad * 4 + r) * N_PIX + n0 + j * 16 + l16];
    f32x4 acc2[2] = {};
    for (int kk = 0; kk < K; kk += 32) {
        const float* ar = wproj + (mrow + l16) * K + kk + quad * 8;
        bf16x8 a;
        for (int j = 0; j < 8; ++j) a[j] = (bf16)ar[j];
        bf16x8 b0 = *(const bf16x8*)(Bld + l16 * 200 + kk + quad * 8);
        bf16x8 b1 = *(const bf16x8*)(Bld + (16 + l16) * 200 + kk + quad * 8);
        acc2[0] = mfma16(a, b0, acc2[0]);
        acc2[1] = mfma16(a, b1, acc2[1]);
    }
    for (int j = 0; j < 2; ++j)
        for (int r = 0; r < 4; ++r) {
            int row = mrow + quad * 4 + r;
            int col = n0 + j * 16 + l16;
            outf[(size_t)row * N_PIX + col] = acc2[j][r] + rv[j * 4 + r];
        }
}

extern "C" void kernel_launch(void* const* d_in, const int* in_sizes, int n_in,
                              void* d_out, int out_size, void* d_ws, size_t ws_size,
                              hipStream_t stream) {
    const float* x     = (const float*)d_in[0];
    const float* gamma = (const float*)d_in[1];
    const float* beta  = (const float*)d_in[2];
    const float* wqkv  = (const float*)d_in[3];
    const float* wdw   = (const float*)d_in[4];
    const float* bdw   = (const float*)d_in[5];
    const float* wproj = (const float*)d_in[6];
    const float* temp  = (const float*)d_in[7];
    float* out = (float*)d_out;

    char* ws = (char*)d_ws;
    bf16* qkv     = (bf16*)(ws + 0);          // 576*4096*2 = 4718592
    bf16* qt      = (bf16*)(ws + 4718592);    // 2097152
    bf16* kt      = (bf16*)(ws + 6815744);    // 2097152
    bf16* vl      = (bf16*)(ws + 8912896);    // 2097152
    bf16* opart   = (bf16*)(ws + 11010048);   // 8*8*4096*24*2 = 12582912
    bf16* lpart   = (bf16*)(ws + 23592960);   // 8*8*4096*2 = 524288
    float* maxk2  = (float*)(ws + 24117248);  // 32

    ln_qkv<<<dim3(64, 9), 256, 0, stream>>>(x, gamma, beta, wqkv, qkv, maxk2);
    dwconv<<<1536, 256, 0, stream>>>(qkv, wdw, bdw, qt, kt, vl, maxk2);
    flash_attn<<<NSPLIT * 128, 256, 0, stream>>>(qt, kt, vl, temp, maxk2, opart, lpart);
    gemm_proj<<<dim3(128, 3), 256, 0, stream>>>(wproj, opart, lpart, out, x);
}

// Round 4
// 131.569 us; speedup vs baseline: 4.6584x; 1.0088x over previous
//
#include <hip/hip_runtime.h>
#include <hip/hip_bf16.h>

// MDTA: LN -> 1x1 conv (QKV) -> dw3x3 -> spatial attention (N=4096, d=24, 8 heads) -> proj + residual
// Round 15: resubmit of round-14 candidate (bench infra failed twice; no measurement taken).
// Flash de-serialization: the 4 q-fragments previously shared one 2KB LDS P-region, forcing
// f+1's P-writes to order behind f's P-reads (same-wave DS in-order + alias waits) -> the 4
// independent fragment pipelines ran as one serial chain. Now each fragment gets its own 2KB
// region (8KB/wave, 32KB/block; 128KB/CU at 4 blocks/CU < 160KB LDS), letting the unrolled
// f-loop software-pipeline. Also: wqkv/wproj weight loads vectorized f32x4 (4x fewer VMEM ops).

typedef __bf16 bf16;
typedef __bf16 bf16x2 __attribute__((ext_vector_type(2)));
typedef __bf16 bf16x4 __attribute__((ext_vector_type(4)));
typedef __bf16 bf16x8 __attribute__((ext_vector_type(8)));
typedef float f32x4 __attribute__((ext_vector_type(4)));

#define C_DIM 192
#define N_PIX 4096
#define HEADS 8
#define DHEAD 24
#define DPAD 32
#define C3 576
#define NSPLIT 8

__device__ inline float fast_exp2(float x) {
#if __has_builtin(__builtin_amdgcn_exp2f)
    return __builtin_amdgcn_exp2f(x);
#else
    return exp2f(x);
#endif
}

__device__ inline f32x4 mfma16(bf16x8 a, bf16x8 b, f32x4 c) {
    return __builtin_amdgcn_mfma_f32_16x16x32_bf16(a, b, c, 0, 0, 0);
}

// ---------------- fused LN + QKV GEMM (64x64 tile): qkv[576,4096] = wqkv[576,192] * LN(x)[4096,192]^T ----------------
__global__ __launch_bounds__(256) void ln_qkv(const float* __restrict__ x,
                                              const float* __restrict__ gamma,
                                              const float* __restrict__ beta,
                                              const float* __restrict__ wqkv,
                                              bf16* __restrict__ qkvb,
                                              float* __restrict__ maxk2) {
    __shared__ __align__(16) bf16 Bt[64 * 200];   // 25.6 KB, +8 pad breaks 32-bank stride
    __shared__ float gs[C_DIM], bs[C_DIM];
    const int K = C_DIM;
    int n0 = blockIdx.x * 64;
    int m0 = blockIdx.y * 64;
    int t = threadIdx.x;
    if (t < C_DIM) { gs[t] = gamma[t]; bs[t] = beta[t]; }
    if (blockIdx.x == 0 && blockIdx.y == 0 && t < 8) maxk2[t] = 0.0f;
    __syncthreads();

    int lane = t & 63, wave = t >> 6;
    {
        int pl = wave * 16 + (lane & 15);       // pixel within tile, 0..63
        int seg = lane >> 4;                    // 0..3 -> 48 channels each
        int p = n0 + pl;
        float v[48];
        float s = 0.f, ss = 0.f;
        for (int j = 0; j < 48; ++j) {
            float f = x[(seg * 48 + j) * N_PIX + p];
            v[j] = f; s += f; ss += f * f;
        }
        s += __shfl_xor(s, 16, 64); s += __shfl_xor(s, 32, 64);
        ss += __shfl_xor(ss, 16, 64); ss += __shfl_xor(ss, 32, 64);
        float mean = s * (1.0f / C_DIM);
        float var = ss * (1.0f / C_DIM) - mean * mean;
        float rstd = rsqrtf(var + 1e-5f);
        bf16* dst = Bt + pl * 200 + seg * 48;
        for (int g = 0; g < 6; ++g) {
            bf16x8 w;
            for (int j = 0; j < 8; ++j) {
                int c = seg * 48 + g * 8 + j;
                w[j] = (bf16)((v[g * 8 + j] - mean) * rstd * gs[c] + bs[c]);
            }
            *(bf16x8*)(dst + g * 8) = w;
        }
    }
    __syncthreads();

    int l16 = lane & 15, quad = lane >> 4;
    int wm = (wave >> 1) * 32, wn = (wave & 1) * 32;
    f32x4 acc[2][2] = {};
    for (int kk = 0; kk < K; kk += 32) {
        const f32x4* ar0 = (const f32x4*)(wqkv + (m0 + wm + l16) * K + kk + quad * 8);
        const f32x4* ar1 = (const f32x4*)(wqkv + (m0 + wm + 16 + l16) * K + kk + quad * 8);
        f32x4 w0a = ar0[0], w0b = ar0[1];
        f32x4 w1a = ar1[0], w1b = ar1[1];
        bf16x8 a0, a1;
        for (int j = 0; j < 4; ++j) {
            a0[j] = (bf16)w0a[j]; a0[4 + j] = (bf16)w0b[j];
            a1[j] = (bf16)w1a[j]; a1[4 + j] = (bf16)w1b[j];
        }
        bf16x8 b0 = *(const bf16x8*)(Bt + (wn + l16) * 200 + kk + quad * 8);
        bf16x8 b1 = *(const bf16x8*)(Bt + (wn + 16 + l16) * 200 + kk + quad * 8);
        acc[0][0] = mfma16(a0, b0, acc[0][0]);
        acc[0][1] = mfma16(a0, b1, acc[0][1]);
        acc[1][0] = mfma16(a1, b0, acc[1][0]);
        acc[1][1] = mfma16(a1, b1, acc[1][1]);
    }
    for (int i = 0; i < 2; ++i)
        for (int j = 0; j < 2; ++j)
            for (int r = 0; r < 4; ++r) {
                int row = m0 + wm + i * 16 + quad * 4 + r;
                int col = n0 + wn + j * 16 + l16;
                qkvb[(size_t)row * N_PIX + col] = (bf16)acc[i][j][r];
            }
}

// ---------------- depthwise 3x3 + bias, vectorized; q/k stores via LDS transpose ----------------
__global__ __launch_bounds__(256) void dwconv(const bf16* __restrict__ qkv,
                                              const float* __restrict__ wdw,
                                              const float* __restrict__ bdw,
                                              bf16* __restrict__ qt,
                                              bf16* __restrict__ kt,
                                              bf16* __restrict__ vl,
                                              float* __restrict__ maxk2) {
    __shared__ float k2s[24][64];
    __shared__ bf16 stg[64 * DPAD];   // [px][ch], 4 KB
    int bx = blockIdx.x;
    int part = bx >> 9;            // 512 blocks per part
    int h = (bx >> 6) & 7;
    int y = bx & 63;
    int t = threadIdx.x;
    int ch_local = t >> 3;         // 0..31 (24 active)
    int seg = t & 7;
    int px0 = seg * 8;
    bool active = ch_local < 24;

    float acc[8];
    if (active) {
        int ch = part * C_DIM + h * DHEAD + ch_local;
        const bf16* in = qkv + (size_t)ch * N_PIX;
        float w[9];
        for (int i = 0; i < 9; ++i) w[i] = wdw[ch * 9 + i];
        float bias = bdw[ch];
        float rowv[3][10];
        for (int r = 0; r < 3; ++r) {
            int yy = y + r - 1;
            if (yy >= 0 && yy < 64) {
                bf16x8 v8 = *(const bf16x8*)(in + yy * 64 + px0);
                for (int j = 0; j < 8; ++j) rowv[r][j + 1] = (float)v8[j];
                rowv[r][0] = (seg > 0) ? (float)in[yy * 64 + px0 - 1] : 0.f;
                rowv[r][9] = (seg < 7) ? (float)in[yy * 64 + px0 + 8] : 0.f;
            } else {
                for (int j = 0; j < 10; ++j) rowv[r][j] = 0.f;
            }
        }
        for (int j = 0; j < 8; ++j) {
            float a = bias;
            for (int r = 0; r < 3; ++r)
                a += w[r * 3 + 0] * rowv[r][j] + w[r * 3 + 1] * rowv[r][j + 1]
                   + w[r * 3 + 2] * rowv[r][j + 2];
            acc[j] = a;
        }
    }

    if (part == 2) {
        if (active) {
            bf16x8 v8;
            for (int j = 0; j < 8; ++j) v8[j] = (bf16)acc[j];
            *(bf16x8*)(vl + ((size_t)(h * DPAD + ch_local)) * N_PIX + y * 64 + px0) = v8;
        } else {
            int i = t - 192;           // pad rows 24..31 x 8 segments
            int dd = 24 + (i >> 3);
            int s2 = i & 7;
            bf16 val = (bf16)((dd == 24) ? 1.0f : 0.0f);
            bf16x8 v8;
            for (int j = 0; j < 8; ++j) v8[j] = val;
            *(bf16x8*)(vl + ((size_t)(h * DPAD + dd)) * N_PIX + y * 64 + s2 * 8) = v8;
        }
    } else {
        if (active) {
            for (int j = 0; j < 8; ++j)
                stg[(px0 + j) * DPAD + ch_local] = (bf16)acc[j];
        } else {
            int i = t - 192;           // px = i: zero pad ch 24..31
            bf16x8 z;
            for (int j = 0; j < 8; ++j) z[j] = (bf16)0.0f;
            *(bf16x8*)(stg + i * DPAD + 24) = z;
        }
        if (part == 1 && active)
            for (int j = 0; j < 8; ++j) k2s[ch_local][px0 + j] = acc[j] * acc[j];
        __syncthreads();
        bf16* dst = (part == 0 ? qt : kt) + ((size_t)h * N_PIX + y * 64) * DPAD;
        *(bf16x8*)(dst + t * 8) = *(const bf16x8*)(stg + t * 8);
        if (part == 1 && t < 64) {
            float s = 0.f;
            for (int c = 0; c < 24; ++c) s += k2s[c][t];
            for (int off = 1; off < 64; off <<= 1)
                s = fmaxf(s, __shfl_xor(s, off, 64));
            if (t == 0) atomicMax((unsigned int*)(maxk2 + h), __float_as_uint(s));
        }
    }
}

// ---------------- flash attention: fat waves, K-prefetch pipeline, per-fragment P buffers ----------------
__global__ __launch_bounds__(256, 4) void flash_attn(const bf16* __restrict__ qt,
                                                     const bf16* __restrict__ kt,
                                                     const bf16* __restrict__ vl,
                                                     const float* __restrict__ temp,
                                                     const float* __restrict__ maxk2,
                                                     bf16* __restrict__ opart,
                                                     bf16* __restrict__ lpart) {
    __shared__ __align__(16) bf16 Plds[16 * 1024];  // 8KB/wave: 4 fragments x 2KB each (no aliasing)

    int tid = threadIdx.x;
    int wave = tid >> 6, lane = tid & 63;
    int l16 = lane & 15, quad = lane >> 4;
    int head = blockIdx.x & 7;               // block -> XCD round-robin: head pinned per XCD
    int qb = (blockIdx.x >> 3) & 15;
    int split = blockIdx.x >> 7;             // 0..7
    int nbase = qb * 256 + wave * 64;
    float tl = temp[head] * 1.44269504f;

    const bf16* qrow = qt + ((size_t)head * N_PIX + nbase) * DPAD;
    bf16x8 aq[4];
    for (int f = 0; f < 4; ++f)
        aq[f] = *(const bf16x8*)(qrow + (size_t)(f * 16 + l16) * DPAD + quad * 8);

    float mk2 = maxk2[head];
    float Bb[4];
    for (int f = 0; f < 4; ++f) {
        float q2 = 0.f;
        for (int j = 0; j < 8; ++j) { float v = (float)aq[f][j]; q2 += v * v; }
        q2 += __shfl_xor(q2, 16, 64);
        q2 += __shfl_xor(q2, 32, 64);
        Bb[f] = fabsf(tl) * sqrtf(q2 * mk2) + 1.0f;
    }

    const bf16* kbase = kt + (size_t)head * N_PIX * DPAD;
    const bf16* vbase = vl + (size_t)head * DPAD * N_PIX;
    bf16* pw = Plds + wave * 4096;           // 4 x 1024 per wave

    f32x4 o0[4] = {}, o1[4] = {};

    const int NITER = 64 / NSPLIT;           // 8
    int mbase = split * NITER * 64;

    // prologue: K fragments for iter 0
    bf16x8 ak[4];
    for (int mt = 0; mt < 4; ++mt)
        ak[mt] = *(const bf16x8*)(kbase + (size_t)(mbase + mt * 16 + l16) * DPAD + quad * 8);

    #pragma unroll 2
    for (int it = 0; it < NITER; ++it) {
        int m0 = mbase + it * 64;
        // V fragments for this iter (consumed late -> latency self-hiding)
        bf16x8 av0 = *(const bf16x8*)(vbase + (size_t)l16 * N_PIX + m0 + quad * 8);
        bf16x8 av1 = *(const bf16x8*)(vbase + (size_t)(16 + l16) * N_PIX + m0 + quad * 8);
        bf16x8 av2 = *(const bf16x8*)(vbase + (size_t)l16 * N_PIX + m0 + 32 + quad * 8);
        bf16x8 av3 = *(const bf16x8*)(vbase + (size_t)(16 + l16) * N_PIX + m0 + 32 + quad * 8);
        // prefetch next iter's K fragments (the latency-exposed loads)
        bf16x8 akn[4];
        if (it + 1 < NITER) {
            int m1 = m0 + 64;
            for (int mt = 0; mt < 4; ++mt)
                akn[mt] = *(const bf16x8*)(kbase + (size_t)(m1 + mt * 16 + l16) * DPAD + quad * 8);
        }

        for (int f = 0; f < 4; ++f) {
            bf16* pwf = pw + f * 1024;       // private region per fragment -> no false DS deps
            f32x4 z = {0.f, 0.f, 0.f, 0.f};
            f32x4 st[4];
            for (int mt = 0; mt < 4; ++mt) st[mt] = mfma16(ak[mt], aq[f], z);
            for (int mt = 0; mt < 4; ++mt) {
                bf16x4 pk;
                for (int r = 0; r < 4; ++r)
                    pk[r] = (bf16)fast_exp2(__builtin_fmaf(st[mt][r], tl, -Bb[f]));
                int chunk = mt * 2 + (quad >> 1);
                *(bf16x4*)(pwf + (chunk * 16 + l16) * 8 + (quad & 1) * 4) = pk;
            }
            bf16x8 ap0 = *(const bf16x8*)(pwf + (quad * 16 + l16) * 8);
            bf16x8 ap1 = *(const bf16x8*)(pwf + ((4 + quad) * 16 + l16) * 8);
            o0[f] = mfma16(av0, ap0, o0[f]);
            o1[f] = mfma16(av1, ap0, o1[f]);
            o0[f] = mfma16(av2, ap1, o0[f]);
            o1[f] = mfma16(av3, ap1, o1[f]);
        }
        if (it + 1 < NITER)
            for (int mt = 0; mt < 4; ++mt) ak[mt] = akn[mt];
    }

    for (int f = 0; f < 4; ++f) {
        int n = nbase + f * 16 + l16;
        size_t rowo = ((size_t)(split * 8 + head) * N_PIX + n) * 24;
        bf16x4 w0;
        for (int r = 0; r < 4; ++r) w0[r] = (bf16)o0[f][r];
        *(bf16x4*)(opart + rowo + quad * 4) = w0;
        if (quad < 2) {
            bf16x4 w1;
            for (int r = 0; r < 4; ++r) w1[r] = (bf16)o1[f][r];
            *(bf16x4*)(opart + rowo + 16 + quad * 4) = w1;
        }
        if (quad == 2)
            lpart[(size_t)(split * 8 + head) * N_PIX + n] = (bf16)o1[f][0];
    }
}

// ---------------- proj GEMM with fused split-K combine; wproj converted inline ----------------
__global__ __launch_bounds__(256) void gemm_proj(const float* __restrict__ wproj,
                                                 const bf16* __restrict__ opart,
                                                 const bf16* __restrict__ lpart,
                                                 float* __restrict__ outf,
                                                 const float* __restrict__ resid) {
    __shared__ __align__(16) bf16 Bld[32 * 200];
    const int K = C_DIM;
    int n0 = blockIdx.x * 32;
    int m0 = blockIdx.y * 64;
    int t = threadIdx.x;
    {
        int h = t >> 5, nl = t & 31;
        int n = n0 + nl;
        float acc[24];
        for (int j = 0; j < 24; ++j) acc[j] = 0.f;
        float l = 0.f;
        for (int s = 0; s < NSPLIT; ++s) {
            const bf16* row = opart + ((size_t)(s * 8 + h) * N_PIX + n) * 24;
            bf16x8 a = *(const bf16x8*)(row);
            bf16x8 b = *(const bf16x8*)(row + 8);
            bf16x8 c = *(const bf16x8*)(row + 16);
            for (int j = 0; j < 8; ++j) {
                acc[j] += (float)a[j];
                acc[8 + j] += (float)b[j];
                acc[16 + j] += (float)c[j];
            }
            l += (float)lpart[(size_t)(s * 8 + h) * N_PIX + n];
        }
        float inv = 1.0f / l;
        bf16* dst = Bld + nl * 200 + h * 24;
        for (int g = 0; g < 3; ++g) {
            bf16x8 w;
            for (int j = 0; j < 8; ++j) w[j] = (bf16)(acc[g * 8 + j] * inv);
            *(bf16x8*)(dst + g * 8) = w;
        }
    }
    __syncthreads();
    int wave = t >> 6, lane = t & 63;
    int l16 = lane & 15, quad = lane >> 4;
    int mrow = m0 + wave * 16;
    float rv[8];
    for (int j = 0; j < 2; ++j)
        for (int r = 0; r < 4; ++r)
            rv[j * 4 + r] = resid[(size_t)(mrow + quad * 4 + r) * N_PIX + n0 + j * 16 + l16];
    f32x4 acc2[2] = {};
    for (int kk = 0; kk < K; kk += 32) {
        const f32x4* ar = (const f32x4*)(wproj + (mrow + l16) * K + kk + quad * 8);
        f32x4 wa = ar[0], wb = ar[1];
        bf16x8 a;
        for (int j = 0; j < 4; ++j) { a[j] = (bf16)wa[j]; a[4 + j] = (bf16)wb[j]; }
        bf16x8 b0 = *(const bf16x8*)(Bld + l16 * 200 + kk + quad * 8);
        bf16x8 b1 = *(const bf16x8*)(Bld + (16 + l16) * 200 + kk + quad * 8);
        acc2[0] = mfma16(a, b0, acc2[0]);
        acc2[1] = mfma16(a, b1, acc2[1]);
    }
    for (int j = 0; j < 2; ++j)
        for (int r = 0; r < 4; ++r) {
            int row = mrow + quad * 4 + r;
            int col = n0 + j * 16 + l16;
            outf[(size_t)row * N_PIX + col] = acc2[j][r] + rv[j * 4 + r];
        }
}

extern "C" void kernel_launch(void* const* d_in, const int* in_sizes, int n_in,
                              void* d_out, int out_size, void* d_ws, size_t ws_size,
                              hipStream_t stream) {
    const float* x     = (const float*)d_in[0];
    const float* gamma = (const float*)d_in[1];
    const float* beta  = (const float*)d_in[2];
    const float* wqkv  = (const float*)d_in[3];
    const float* wdw   = (const float*)d_in[4];
    const float* bdw   = (const float*)d_in[5];
    const float* wproj = (const float*)d_in[6];
    const float* temp  = (const float*)d_in[7];
    float* out = (float*)d_out;

    char* ws = (char*)d_ws;
    bf16* qkv     = (bf16*)(ws + 0);          // 576*4096*2 = 4718592
    bf16* qt      = (bf16*)(ws + 4718592);    // 2097152
    bf16* kt      = (bf16*)(ws + 6815744);    // 2097152
    bf16* vl      = (bf16*)(ws + 8912896);    // 2097152
    bf16* opart   = (bf16*)(ws + 11010048);   // 8*8*4096*24*2 = 12582912
    bf16* lpart   = (bf16*)(ws + 23592960);   // 8*8*4096*2 = 524288
    float* maxk2  = (float*)(ws + 24117248);  // 32

    ln_qkv<<<dim3(64, 9), 256, 0, stream>>>(x, gamma, beta, wqkv, qkv, maxk2);
    dwconv<<<1536, 256, 0, stream>>>(qkv, wdw, bdw, qt, kt, vl, maxk2);
    flash_attn<<<NSPLIT * 128, 256, 0, stream>>>(qt, kt, vl, temp, maxk2, opart, lpart);
    gemm_proj<<<dim3(128, 3), 256, 0, stream>>>(wproj, opart, lpart, out, x);
}